// Round 7
// baseline (198.123 us; speedup 1.0000x reference)
//
#include <hip/hip_runtime.h>
#include <math.h>

#define SEQL   2048
#define NBATCH 2
#define DMODEL 768
#define DINNER 1536
#define D2     3072
#define DSTATE 16
#define DHID   384
#define ROWS   (NBATCH*SEQL)   /* 4096 */
#define NC     64              /* scan chunks */
#define CL     32              /* chunk length */
#define LN_EPSF 1e-5f

typedef unsigned short u16;
typedef short bf16x8 __attribute__((ext_vector_type(8)));
typedef float f32x4 __attribute__((ext_vector_type(4)));

// fp32 -> bf16 round-to-nearest-even
__device__ __forceinline__ u16 f2b(float x) {
  unsigned u = __float_as_uint(x);
  unsigned r = (u + 0x7FFFu + ((u >> 16) & 1u)) >> 16;
  return (u16)r;
}
__device__ __forceinline__ float b2f(u16 v) {
  return __uint_as_float((unsigned)v << 16);
}

// E[n] = exp(-dl)^(n+1), n=0..15 — 1 exp + 15 muls (log-depth ladder).
// Valid when A[d][n] == -(n+1) (device-verified via flag).
__device__ __forceinline__ void build_E_fast(float dl, float* E) {
  float e1 = __expf(-dl);
  float e2 = e1 * e1, e4 = e2 * e2, e8 = e4 * e4;
  E[0] = e1;      E[1] = e2;      E[2] = e2 * e1; E[3] = e4;
  E[4] = e4 * e1; E[5] = e4 * e2; E[6] = e4 * E[2]; E[7] = e8;
  E[8] = e8 * e1; E[9] = e8 * e2; E[10] = e8 * E[2]; E[11] = e8 * e4;
  E[12] = e8 * E[4]; E[13] = e8 * E[5]; E[14] = e8 * E[6]; E[15] = e8 * e8;
}

// ---------------- block reduce helper (256 threads, 4 waves) ----------------
__device__ __forceinline__ float block_reduce_sum(float v, float* red) {
  #pragma unroll
  for (int o = 32; o > 0; o >>= 1) v += __shfl_xor(v, o);
  int tid = threadIdx.x;
  int wid = tid >> 6;
  if ((tid & 63) == 0) red[wid] = v;
  __syncthreads();
  float s = red[0] + red[1] + red[2] + red[3];
  __syncthreads();
  return s;
}

// ---------------- combined prep kernel -------------------------------------
// Block ranges (all 256-thread blocks):
//  [0,2304)      : W_in  [768][3072]  -> Wt_in  [3072][768]  bf16
//  [2304,2880)   : Wc2   [384][1536]  -> Wt_c2  [1536][384]  bf16
//  [2880,4032)   : W_out [1536][768]  -> Wt_out [768][1536]  bf16
//  [4032,4416)   : W_x   [1536][33]   -> Wxt    [64][1536]   bf16 zero-pad
//  [4416,10560)  : hid = relu(imp*Wc1+bc1) -> bf16
//  [10560,14656) : LayerNorm -> xnb bf16
__device__ __forceinline__ void tconv_body(const float* __restrict__ src,
    u16* __restrict__ dst, int K, int N, int bx, int by, int tid) {
  __shared__ float t[32][33];
  int n0 = bx * 32, k0 = by * 32;
  int tx = tid & 31, ty = tid >> 5;  // 32 x 8
  #pragma unroll
  for (int rr = 0; rr < 32; rr += 8)
    t[ty + rr][tx] = src[(long)(k0 + ty + rr) * N + n0 + tx];
  __syncthreads();
  #pragma unroll
  for (int rr = 0; rr < 32; rr += 8)
    dst[(long)(n0 + ty + rr) * K + k0 + tx] = f2b(t[tx][ty + rr]);
}

__global__ __launch_bounds__(256) void prep_kernel(
    const float* __restrict__ W_in,  u16* __restrict__ Wt_in,
    const float* __restrict__ Wc2,   u16* __restrict__ Wt_c2,
    const float* __restrict__ W_out, u16* __restrict__ Wt_out,
    const float* __restrict__ Wx,    u16* __restrict__ Wxt,
    const float* __restrict__ imp,   const float* __restrict__ Wc1,
    const float* __restrict__ bc1,   u16* __restrict__ hid,
    const float* __restrict__ x,     const float* __restrict__ g,
    const float* __restrict__ bta,   u16* __restrict__ xn) {
  int id = blockIdx.x;
  int tid = threadIdx.x;
  if (id < 2304) {
    tconv_body(W_in, Wt_in, 768, 3072, id % 96, id / 96, tid);
  } else if (id < 2880) {
    int r = id - 2304; tconv_body(Wc2, Wt_c2, 384, 1536, r % 48, r / 48, tid);
  } else if (id < 4032) {
    int r = id - 2880; tconv_body(W_out, Wt_out, 1536, 768, r % 24, r / 24, tid);
  } else if (id < 4416) {
    int idx = (id - 4032) * 256 + tid;   // over 64*1536
    int n = idx / 1536, k = idx % 1536;
    Wxt[idx] = (n < 33) ? f2b(Wx[k * 33 + n]) : (u16)0;
  } else if (id < 10560) {
    long idx = (long)(id - 4416) * 256 + tid;  // over ROWS*DHID
    int j = (int)(idx % DHID);
    long r = idx / DHID;
    float v = fmaf(imp[r], Wc1[j], bc1[j]);
    hid[idx] = f2b(v > 0.f ? v : 0.f);
  } else {
    __shared__ float red[4];
    int r = id - 10560;
    const float* xr = x + (long)r * DMODEL;
    float v0 = xr[tid], v1 = xr[tid + 256], v2 = xr[tid + 512];
    float mu = block_reduce_sum(v0 + v1 + v2, red) * (1.f / DMODEL);
    float d0 = v0 - mu, d1 = v1 - mu, d2 = v2 - mu;
    float var = block_reduce_sum(d0*d0 + d1*d1 + d2*d2, red) * (1.f / DMODEL);
    float rs = rsqrtf(var + LN_EPSF);
    u16* o = xn + (long)r * DMODEL;
    o[tid]       = f2b(d0 * rs * g[tid]       + bta[tid]);
    o[tid + 256] = f2b(d1 * rs * g[tid + 256] + bta[tid + 256]);
    o[tid + 512] = f2b(d2 * rs * g[tid + 512] + bta[tid + 512]);
  }
}

// ---------------- Af = -exp(A_log); flag = #mismatch (single block) ---------
__global__ __launch_bounds__(256) void af_kernel(const float* __restrict__ A_log,
    float* __restrict__ Af, int* __restrict__ flag) {
  __shared__ int scnt;
  int tid = threadIdx.x;
  if (tid == 0) scnt = 0;
  __syncthreads();
  int mism = 0;
  for (int i = tid; i < DINNER * 16; i += 256) {
    int n = i & 15;
    float a = -expf(A_log[i]);
    Af[i] = a;
    mism += (fabsf(a + (float)(n + 1)) > 1e-3f) ? 1 : 0;
  }
  atomicAdd(&scnt, mism);
  __syncthreads();
  if (tid == 0) *flag = scnt;
}

// ---------------- bf16 MFMA GEMM: C[M][N] fp32 = A[M][K]bf16 @ Bt[N][K]bf16 --
// BM x BN tile, BK=64, 256 threads (4 waves, WGM x WGN wave grid).
// LDS layout [rows][64] bf16, XOR-swizzled: byte ^= ((row&7)<<4); staging
// pre-swizzles the *global* source so global_load_lds's linear write lands
// the swizzled layout (m173/m201 pattern).
// DOUBLE-BUFFERED 2-phase pipeline (T3 minimum template, m248-verified).
// XCD-aware bijective blockIdx swizzle (T1): requires nwg % 8 == 0.
// EPI: 0 = plain fp32
//      1 = +aux residual
//      2 = delta epilogue (p1=W_dt, p2=b_dt, p3=bc2, aux=xs64; raw=aux[row*64])
//      4 = split: cols < N/2 -> C fp32 (stride N/2); cols >= N/2 -> pz bf16
template<int BM, int BN, int WGM, int WGN, int EPI>
__global__ __launch_bounds__(256) void gemm_bf16(
    const u16* __restrict__ A, const u16* __restrict__ Bt,
    float* __restrict__ C, int M, int N, int K, const float* __restrict__ aux,
    const float* __restrict__ p1, const float* __restrict__ p2,
    const float* __restrict__ p3, u16* __restrict__ pz) {
  constexpr int MF = BM / (16 * WGM);
  constexpr int NF = BN / (16 * WGN);
  constexpr int AR = BM / 32;   // A staging rounds
  constexpr int BR = BN / 32;   // B staging rounds
  constexpr int HALF = (BM + BN) * 128;   // bytes per buffer
  __shared__ __align__(16) char smem[2 * HALF];

  int tid = threadIdx.x;
  int lane = tid & 63;
  int wid = tid >> 6;

  // T1: XCD-aware bijective swizzle (nwg % 8 == 0 at all call sites)
  int nwg = gridDim.x * gridDim.y;
  int bid = blockIdx.y * gridDim.x + blockIdx.x;
  int q = nwg >> 3;
  int swz = (bid & 7) * q + (bid >> 3);
  int bx = swz % gridDim.x, by = swz / gridDim.x;

  int m0 = by * BM, n0 = bx * BN;
  int wr = wid / WGN, wc = wid % WGN;

  f32x4 acc[MF][NF];
  #pragma unroll
  for (int i = 0; i < MF; ++i)
    #pragma unroll
    for (int j = 0; j < NF; ++j) acc[i][j] = f32x4{0.f, 0.f, 0.f, 0.f};

  int srow = tid >> 3;            // 0..31 within a staging round
  int schunk = tid & 7;           // LDS 16B-chunk index within row
  int wavebase = (tid & 192) * 16;   // wave-uniform LDS byte base (wid*1024)
  int arow = lane & 15;
  int kgrp = lane >> 4;           // 0..3
  int sw = (lane & 7) << 4;       // read-side XOR swizzle

  // stage tile (k-offset k0) into LDS buffer `base`
  auto stage = [&](int k0, char* base) {
    #pragma unroll
    for (int r = 0; r < AR; ++r) {
      int row = r * 32 + srow;
      int chunk = schunk ^ (row & 7);
      const u16* g = A + (size_t)(m0 + row) * K + k0 + chunk * 8;
      __builtin_amdgcn_global_load_lds(
          (const __attribute__((address_space(1))) void*)g,
          (__attribute__((address_space(3))) void*)(base + r * 4096 + wavebase),
          16, 0, 0);
    }
    #pragma unroll
    for (int r = 0; r < BR; ++r) {
      int row = r * 32 + srow;
      int chunk = schunk ^ (row & 7);
      const u16* g = Bt + (size_t)(n0 + row) * K + k0 + chunk * 8;
      __builtin_amdgcn_global_load_lds(
          (const __attribute__((address_space(1))) void*)g,
          (__attribute__((address_space(3))) void*)(base + BM * 128 + r * 4096 + wavebase),
          16, 0, 0);
    }
  };

  // MFMA over one staged K-tile in buffer `base`
  auto compute = [&](const char* base) {
    const char* Asm = base;
    const char* Bsm = base + BM * 128;
    #pragma unroll
    for (int ks = 0; ks < 2; ++ks) {
      bf16x8 af[MF], bg[NF];
      #pragma unroll
      for (int i = 0; i < MF; ++i) {
        int row = wr * MF * 16 + i * 16 + arow;
        int off = row * 128 + ((((ks * 4 + kgrp) * 16)) ^ sw);
        af[i] = *(const bf16x8*)(Asm + off);
      }
      #pragma unroll
      for (int j = 0; j < NF; ++j) {
        int row = wc * NF * 16 + j * 16 + arow;
        int off = row * 128 + ((((ks * 4 + kgrp) * 16)) ^ sw);
        bg[j] = *(const bf16x8*)(Bsm + off);
      }
      #pragma unroll
      for (int i = 0; i < MF; ++i)
        #pragma unroll
        for (int j = 0; j < NF; ++j)
          acc[i][j] = __builtin_amdgcn_mfma_f32_16x16x32_bf16(af[i], bg[j], acc[i][j], 0, 0, 0);
    }
  };

  int nk = K >> 6;   // even for all call sites (12/24/6/24)
  stage(0, smem);
  asm volatile("s_waitcnt vmcnt(0)" ::: "memory");
  __builtin_amdgcn_s_barrier();
  for (int t = 0; t < nk; t += 2) {
    stage((t + 1) << 6, smem + HALF);        // prefetch t+1 (t+1<nk: nk even)
    compute(smem);                            // tile t
    asm volatile("s_waitcnt vmcnt(0)" ::: "memory");
    __builtin_amdgcn_s_barrier();
    if (t + 2 < nk) stage((t + 2) << 6, smem);  // prefetch t+2
    compute(smem + HALF);                     // tile t+1
    asm volatile("s_waitcnt vmcnt(0)" ::: "memory");
    __builtin_amdgcn_s_barrier();
  }

  // epilogue: D row=(lane>>4)*4+r, col=lane&15 (m89-verified)
  int crow0 = m0 + wr * MF * 16 + (lane >> 4) * 4;
  int ccol0 = n0 + wc * NF * 16 + (lane & 15);
  #pragma unroll
  for (int i = 0; i < MF; ++i) {
    #pragma unroll
    for (int r = 0; r < 4; ++r) {
      int row = crow0 + i * 16 + r;
      float araw = 0.f;
      if (EPI == 2) araw = aux[(size_t)row * 64];
      #pragma unroll
      for (int j = 0; j < NF; ++j) {
        int col = ccol0 + j * 16;
        float v = acc[i][j][r];
        if (EPI == 0) {
          C[(size_t)row * N + col] = v;
        } else if (EPI == 1) {
          C[(size_t)row * N + col] = v + aux[(size_t)row * N + col];
        } else if (EPI == 2) {
          float raw = fmaf(araw, p1[col], p2[col]);
          float sp = fmaxf(raw, 0.f) + __logf(1.f + __expf(-fabsf(raw)));
          float mod = 1.f / (1.f + __expf(-(v + p3[col])));
          C[(size_t)row * N + col] = sp * (1.f + mod);
        } else if (EPI == 4) {
          int half = N >> 1;
          if (col < half) C[(size_t)row * half + col] = v;
          else            pz[(size_t)row * half + (col - half)] = f2b(v);
        }
      }
    }
  }
}

// ---------------- 3. depthwise causal conv (k=4) + bias + SiLU ---------------
// reads contiguous x_proj [ROWS][DINNER] fp32;
// writes fp32 xc (for scan) and bf16 xcb (for the x_ssm MFMA GEMM)
__global__ __launch_bounds__(256) void conv_silu_kernel(const float* __restrict__ xp,
    const float* __restrict__ cw, const float* __restrict__ cb,
    float* __restrict__ xc, u16* __restrict__ xcb) {
  long idx = (long)blockIdx.x * 256 + threadIdx.x;
  if (idx >= (long)ROWS * DINNER) return;
  int d = (int)(idx % DINNER);
  long r = idx / DINNER;
  int s = (int)(r % SEQL);
  long b = r / SEQL;
  float acc = cb[d];
  #pragma unroll
  for (int j = 0; j < 4; ++j) {
    int ss = s - 3 + j;
    if (ss >= 0)
      acc = fmaf(xp[(b * SEQL + ss) * (long)DINNER + d], cw[d * 4 + j], acc);
  }
  float sg = 1.f / (1.f + __expf(-acc));
  float v = acc * sg;
  xc[idx] = v;
  xcb[idx] = f2b(v);
}

// ---------------- 7. scan phase 1: per-chunk local states + sum(delta) ------
__global__ __launch_bounds__(256) void scan_p1(const float* __restrict__ dlt,
    const float* __restrict__ xc, const float* __restrict__ xs,
    const float* __restrict__ Af, const int* __restrict__ flag,
    float* __restrict__ Hloc, float* __restrict__ sdl) {
  __shared__ float Bsh[CL][16];
  int tid = threadIdx.x;
  int dblk = blockIdx.x % (DINNER / 256);
  int c = (blockIdx.x / (DINNER / 256)) % NC;
  int b = blockIdx.x / ((DINNER / 256) * NC);
  int d = dblk * 256 + tid;
  long row0 = (long)b * SEQL + c * CL;
  for (int e = tid; e < CL * 16; e += 256) {
    int t = e >> 4, n = e & 15;
    Bsh[t][n] = xs[(row0 + t) * 64 + 1 + n];
  }
  bool fast = (*flag == 0);
  float Ac[16];
  if (!fast) {
    #pragma unroll
    for (int n = 0; n < 16; ++n) Ac[n] = Af[d * 16 + n];
  }
  __syncthreads();
  float h[16] = {};
  float sd = 0.f;
  const float* dp = dlt + row0 * DINNER + d;
  const float* xp = xc + row0 * DINNER + d;
  if (fast) {
    for (int t = 0; t < CL; ++t) {
      float dl = dp[(long)t * DINNER];
      float xv = xp[(long)t * DINNER];
      sd += dl;
      float dx = dl * xv;
      float E[16]; build_E_fast(dl, E);
      #pragma unroll
      for (int n = 0; n < 16; ++n) h[n] = fmaf(E[n], h[n], dx * Bsh[t][n]);
    }
  } else {
    for (int t = 0; t < CL; ++t) {
      float dl = dp[(long)t * DINNER];
      float xv = xp[(long)t * DINNER];
      sd += dl;
      float dx = dl * xv;
      #pragma unroll
      for (int n = 0; n < 16; ++n)
        h[n] = fmaf(__expf(dl * Ac[n]), h[n], dx * Bsh[t][n]);
    }
  }
  long base = ((long)(b * NC + c) * DINNER + d) * 16;
  #pragma unroll
  for (int n = 0; n < 16; ++n) Hloc[base + n] = h[n];
  sdl[(long)(b * NC + c) * DINNER + d] = sd;
}

// ---------------- 8. scan phase 2: carry sweep -------------------------------
__global__ __launch_bounds__(256) void scan_carry(float* __restrict__ Hloc,
    const float* __restrict__ sdl, const float* __restrict__ Af) {
  long g = (long)blockIdx.x * 256 + threadIdx.x;
  if (g >= (long)NBATCH * DINNER * 16) return;
  int n = (int)(g & 15);
  int d = (int)((g >> 4) % DINNER);
  int b = (int)(g / (16L * DINNER));
  float An = Af[d * 16 + n];
  float s = 0.f;
  for (int c = 0; c < NC; ++c) {
    long off = ((long)(b * NC + c) * DINNER + d) * 16 + n;
    float H = Hloc[off];
    float sdv = sdl[(long)(b * NC + c) * DINNER + d];
    Hloc[off] = s;
    s = fmaf(__expf(An * sdv), s, H);
  }
}

// ---------------- 9. scan phase 3: replay + fused gate -> y2 (bf16) ----------
__global__ __launch_bounds__(256) void scan_p3(const float* __restrict__ dlt,
    const float* __restrict__ xc, const float* __restrict__ xs,
    const float* __restrict__ Af, const int* __restrict__ flag,
    const float* __restrict__ Hloc, const u16* __restrict__ zb,
    const float* __restrict__ Dskip, u16* __restrict__ y2) {
  __shared__ float Bsh[CL][16];
  __shared__ float Csh[CL][16];
  int tid = threadIdx.x;
  int dblk = blockIdx.x % (DINNER / 256);
  int c = (blockIdx.x / (DINNER / 256)) % NC;
  int b = blockIdx.x / ((DINNER / 256) * NC);
  int d = dblk * 256 + tid;
  long row0 = (long)b * SEQL + c * CL;
  for (int e = tid; e < CL * 16; e += 256) {
    int t = e >> 4, n = e & 15;
    long rr = row0 + t;
    Bsh[t][n] = xs[rr * 64 + 1 + n];
    Csh[t][n] = xs[rr * 64 + 17 + n];
  }
  bool fast = (*flag == 0);
  float Ac[16];
  if (!fast) {
    #pragma unroll
    for (int n = 0; n < 16; ++n) Ac[n] = Af[d * 16 + n];
  }
  __syncthreads();
  float h[16];
  long base = ((long)(b * NC + c) * DINNER + d) * 16;
  #pragma unroll
  for (int n = 0; n < 16; ++n) h[n] = Hloc[base + n];
  float Dv = Dskip[d];
  const float* dp = dlt + row0 * DINNER + d;
  const float* xp = xc + row0 * DINNER + d;
  const u16* zp = zb + row0 * DINNER + d;
  u16* yp = y2 + row0 * DINNER + d;
  if (fast) {
    for (int t = 0; t < CL; ++t) {
      float dl = dp[(long)t * DINNER];
      float xv = xp[(long)t * DINNER];
      float dx = dl * xv;
      float E[16]; build_E_fast(dl, E);
      float y = 0.f;
      #pragma unroll
      for (int n = 0; n < 16; ++n) {
        h[n] = fmaf(E[n], h[n], dx * Bsh[t][n]);
        y = fmaf(h[n], Csh[t][n], y);
      }
      float yv = fmaf(xv, Dv, y);
      float zv = b2f(zp[(long)t * DINNER]);
      float sz = zv / (1.f + __expf(-zv));
      yp[(long)t * DINNER] = f2b(yv * sz);
    }
  } else {
    for (int t = 0; t < CL; ++t) {
      float dl = dp[(long)t * DINNER];
      float xv = xp[(long)t * DINNER];
      float dx = dl * xv;
      float y = 0.f;
      #pragma unroll
      for (int n = 0; n < 16; ++n) {
        h[n] = fmaf(__expf(dl * Ac[n]), h[n], dx * Bsh[t][n]);
        y = fmaf(h[n], Csh[t][n], y);
      }
      float yv = fmaf(xv, Dv, y);
      float zv = b2f(zp[(long)t * DINNER]);
      float sz = zv / (1.f + __expf(-zv));
      yp[(long)t * DINNER] = f2b(yv * sz);
    }
  }
}

// ---------------- launch ----------------
extern "C" void kernel_launch(void* const* d_in, const int* in_sizes, int n_in,
                              void* d_out, int out_size, void* d_ws, size_t ws_size,
                              hipStream_t stream) {
  const float* x      = (const float*)d_in[0];
  const float* imp    = (const float*)d_in[1];
  const float* ln_g   = (const float*)d_in[2];
  const float* ln_b   = (const float*)d_in[3];
  const float* W_in   = (const float*)d_in[4];
  const float* conv_w = (const float*)d_in[5];
  const float* conv_b = (const float*)d_in[6];
  const float* W_x    = (const float*)d_in[7];
  const float* W_dt   = (const float*)d_in[8];
  const float* b_dt   = (const float*)d_in[9];
  const float* Wc1    = (const float*)d_in[10];
  const float* bc1    = (const float*)d_in[11];
  const float* Wc2    = (const float*)d_in[12];
  const float* bc2    = (const float*)d_in[13];
  const float* A_log  = (const float*)d_in[14];
  const float* Dskip  = (const float*)d_in[15];
  const float* W_out  = (const float*)d_in[16];
  float* out = (float*)d_out;

  char* ws = (char*)d_ws;
  float* xproj  = (float*)(ws);                 // 4096*1536 f32   (25165824)
  float* xc     = (float*)(ws + 25165824L);     // 4096*1536 f32   (25165824)
  float* dlt    = (float*)(ws + 50331648L);     // 4096*1536 f32   (25165824)
  u16*   zb     = (u16*)  (ws + 75497472L);     // 4096*1536 bf16  (12582912)
  float* xs64   = (float*)(ws + 88080384L);     // 4096*64 f32     (1048576)
  u16*   hid    = (u16*)  (ws + 89128960L);     // 4096*384 bf16   (3145728)
  u16*   xnb    = (u16*)  (ws + 92274688L);     // 4096*768 bf16   (6291456)
  u16*   y2     = (u16*)  (ws + 98566144L);     // 4096*1536 bf16  (12582912) [alias xcb]
  u16*   xcb    = (u16*)  (ws + 98566144L);     // alias: dead before y2 written
  float* Hloc   = (float*)(ws + 111149056L);    // 2*64*1536*16 f32 (12582912)
  float* sdl    = (float*)(ws + 123731968L);    // 2*64*1536 f32   (786432)
  u16*   Wt_in  = (u16*)  (ws + 124518400L);    // 3072*768 bf16   (4718592)
  u16*   Wt_c2  = (u16*)  (ws + 129236992L);    // 1536*384 bf16   (1179648)
  u16*   Wt_out = (u16*)  (ws + 130416640L);    // 768*1536 bf16   (2359296)
  u16*   Wxt    = (u16*)  (ws + 132775936L);    // 64*1536 bf16    (196608)
  float* Af     = (float*)(ws + 132972544L);    // 1536*16 f32     (98304)
  int*   flag   = (int*)  (ws + 133070848L);    // 4

  // 0. combined prep: weight transposes + wxt + hid + LN  (input-only deps)
  prep_kernel<<<14656, 256, 0, stream>>>(
      W_in, Wt_in, Wc2, Wt_c2, W_out, Wt_out, W_x, Wxt,
      imp, Wc1, bc1, hid, x, ln_g, ln_b, xnb);
  // 0b. Af + structure flag (single block, no memset needed)
  af_kernel<<<1, 256, 0, stream>>>(A_log, Af, flag);

  // 2. xz = xn @ W_in (4096 x 768 x 3072), split epilogue:
  //    cols 0..1535 -> xproj fp32 ; cols 1536..3071 -> zb bf16
  gemm_bf16<128,128,2,2,4><<<dim3(D2/128, ROWS/128), 256, 0, stream>>>(
      xnb, Wt_in, xproj, ROWS, D2, DMODEL, nullptr, nullptr, nullptr, nullptr, zb);
  // 3. conv + SiLU -> xc (fp32) + xcb (bf16)
  conv_silu_kernel<<<(ROWS * DINNER) / 256, 256, 0, stream>>>(xproj, conv_w, conv_b, xc, xcb);
  // 4. x_ssm = xc @ W_x  (MFMA, N padded 33->64) -> xs64   (BM=32: 128 blocks)
  gemm_bf16<32,64,1,4,0><<<dim3(1, ROWS/32), 256, 0, stream>>>(
      xcb, Wxt, xs64, ROWS, 64, DINNER, nullptr, nullptr, nullptr, nullptr, nullptr);
  // 6. dlt = softplus(xs64[:,0]*Wdt+bdt) * (1+sigmoid(hid@Wc2 + bc2))  (fused)
  gemm_bf16<64,128,1,4,2><<<dim3(DINNER/128, ROWS/64), 256, 0, stream>>>(
      hid, Wt_c2, dlt, ROWS, DINNER, DHID, xs64, W_dt, b_dt, bc2, nullptr);
  // 7-9. chunked scan
  scan_p1<<<NBATCH * NC * (DINNER / 256), 256, 0, stream>>>(dlt, xc, xs64, Af, flag, Hloc, sdl);
  scan_carry<<<(NBATCH * DINNER * 16) / 256, 256, 0, stream>>>(Hloc, sdl, Af);
  scan_p3<<<NBATCH * NC * (DINNER / 256), 256, 0, stream>>>(dlt, xc, xs64, Af, flag, Hloc, zb, Dskip, y2);
  // 10. out = y2 @ W_out + residual  (4096 x 1536 x 768)
  gemm_bf16<64,64,1,4,1><<<dim3(DMODEL/64, ROWS/64), 256, 0, stream>>>(
      y2, Wt_out, out, ROWS, DMODEL, DINNER, x, nullptr, nullptr, nullptr, nullptr);
}

// Round 8
// 191.801 us; speedup vs baseline: 1.0330x; 1.0330x over previous
//
#include <hip/hip_runtime.h>
#include <math.h>

#define SEQL   2048
#define NBATCH 2
#define DMODEL 768
#define DINNER 1536
#define D2     3072
#define DSTATE 16
#define DHID   384
#define ROWS   (NBATCH*SEQL)   /* 4096 */
#define NC     64              /* scan chunks */
#define CL     32              /* chunk length */
#define LN_EPSF 1e-5f

typedef unsigned short u16;
typedef short bf16x8 __attribute__((ext_vector_type(8)));
typedef float f32x4 __attribute__((ext_vector_type(4)));

// fp32 -> bf16 round-to-nearest-even
__device__ __forceinline__ u16 f2b(float x) {
  unsigned u = __float_as_uint(x);
  unsigned r = (u + 0x7FFFu + ((u >> 16) & 1u)) >> 16;
  return (u16)r;
}
__device__ __forceinline__ float b2f(u16 v) {
  return __uint_as_float((unsigned)v << 16);
}

// E[n] = exp(-dl)^(n+1), n=0..15 — 1 exp + 15 muls (log-depth ladder).
// Valid when A[d][n] == -(n+1) (device-verified via flag).
__device__ __forceinline__ void build_E_fast(float dl, float* E) {
  float e1 = __expf(-dl);
  float e2 = e1 * e1, e4 = e2 * e2, e8 = e4 * e4;
  E[0] = e1;      E[1] = e2;      E[2] = e2 * e1; E[3] = e4;
  E[4] = e4 * e1; E[5] = e4 * e2; E[6] = e4 * E[2]; E[7] = e8;
  E[8] = e8 * e1; E[9] = e8 * e2; E[10] = e8 * E[2]; E[11] = e8 * e4;
  E[12] = e8 * E[4]; E[13] = e8 * E[5]; E[14] = e8 * E[6]; E[15] = e8 * e8;
}

// ---------------- block reduce helper (256 threads, 4 waves) ----------------
__device__ __forceinline__ float block_reduce_sum(float v, float* red) {
  #pragma unroll
  for (int o = 32; o > 0; o >>= 1) v += __shfl_xor(v, o);
  int tid = threadIdx.x;
  int wid = tid >> 6;
  if ((tid & 63) == 0) red[wid] = v;
  __syncthreads();
  float s = red[0] + red[1] + red[2] + red[3];
  __syncthreads();
  return s;
}

// ---------------- combined prep kernel -------------------------------------
__device__ __forceinline__ void tconv_body(const float* __restrict__ src,
    u16* __restrict__ dst, int K, int N, int bx, int by, int tid) {
  __shared__ float t[32][33];
  int n0 = bx * 32, k0 = by * 32;
  int tx = tid & 31, ty = tid >> 5;  // 32 x 8
  #pragma unroll
  for (int rr = 0; rr < 32; rr += 8)
    t[ty + rr][tx] = src[(long)(k0 + ty + rr) * N + n0 + tx];
  __syncthreads();
  #pragma unroll
  for (int rr = 0; rr < 32; rr += 8)
    dst[(long)(n0 + ty + rr) * K + k0 + tx] = f2b(t[tx][ty + rr]);
}

__global__ __launch_bounds__(256) void prep_kernel(
    const float* __restrict__ W_in,  u16* __restrict__ Wt_in,
    const float* __restrict__ Wc2,   u16* __restrict__ Wt_c2,
    const float* __restrict__ W_out, u16* __restrict__ Wt_out,
    const float* __restrict__ Wx,    u16* __restrict__ Wxt,
    const float* __restrict__ imp,   const float* __restrict__ Wc1,
    const float* __restrict__ bc1,   u16* __restrict__ hid,
    const float* __restrict__ x,     const float* __restrict__ g,
    const float* __restrict__ bta,   u16* __restrict__ xn) {
  int id = blockIdx.x;
  int tid = threadIdx.x;
  if (id < 2304) {
    tconv_body(W_in, Wt_in, 768, 3072, id % 96, id / 96, tid);
  } else if (id < 2880) {
    int r = id - 2304; tconv_body(Wc2, Wt_c2, 384, 1536, r % 48, r / 48, tid);
  } else if (id < 4032) {
    int r = id - 2880; tconv_body(W_out, Wt_out, 1536, 768, r % 24, r / 24, tid);
  } else if (id < 4416) {
    int idx = (id - 4032) * 256 + tid;   // over 64*1536
    int n = idx / 1536, k = idx % 1536;
    Wxt[idx] = (n < 33) ? f2b(Wx[k * 33 + n]) : (u16)0;
  } else if (id < 10560) {
    long idx = (long)(id - 4416) * 256 + tid;  // over ROWS*DHID
    int j = (int)(idx % DHID);
    long r = idx / DHID;
    float v = fmaf(imp[r], Wc1[j], bc1[j]);
    hid[idx] = f2b(v > 0.f ? v : 0.f);
  } else {
    __shared__ float red[4];
    int r = id - 10560;
    const float* xr = x + (long)r * DMODEL;
    float v0 = xr[tid], v1 = xr[tid + 256], v2 = xr[tid + 512];
    float mu = block_reduce_sum(v0 + v1 + v2, red) * (1.f / DMODEL);
    float d0 = v0 - mu, d1 = v1 - mu, d2 = v2 - mu;
    float var = block_reduce_sum(d0*d0 + d1*d1 + d2*d2, red) * (1.f / DMODEL);
    float rs = rsqrtf(var + LN_EPSF);
    u16* o = xn + (long)r * DMODEL;
    o[tid]       = f2b(d0 * rs * g[tid]       + bta[tid]);
    o[tid + 256] = f2b(d1 * rs * g[tid + 256] + bta[tid + 256]);
    o[tid + 512] = f2b(d2 * rs * g[tid + 512] + bta[tid + 512]);
  }
}

// ---------------- Af = -exp(A_log); flag = #mismatch (single block) ---------
__global__ __launch_bounds__(256) void af_kernel(const float* __restrict__ A_log,
    float* __restrict__ Af, int* __restrict__ flag) {
  __shared__ int scnt;
  int tid = threadIdx.x;
  if (tid == 0) scnt = 0;
  __syncthreads();
  int mism = 0;
  for (int i = tid; i < DINNER * 16; i += 256) {
    int n = i & 15;
    float a = -expf(A_log[i]);
    Af[i] = a;
    mism += (fabsf(a + (float)(n + 1)) > 1e-3f) ? 1 : 0;
  }
  atomicAdd(&scnt, mism);
  __syncthreads();
  if (tid == 0) *flag = scnt;
}

// ---------------- bf16 MFMA GEMM: C[M][N] fp32 = A[M][K]bf16 @ Bt[N][K]bf16 --
// BM x BN tile, BK=64, 256 threads (4 waves, WGM x WGN wave grid).
// LDS layout [rows][64] bf16, XOR-swizzled: byte ^= ((row&7)<<4); staging
// pre-swizzles the *global* source so global_load_lds's linear write lands
// the swizzled layout (m173/m201 pattern).
// DOUBLE-BUFFERED 2-phase pipeline (T3 minimum template, m248-verified).
// No XCD swizzle: all operands are L3-resident (T1 costs ~2% when L3-fit, m160).
// EPI: 0 = plain fp32
//      1 = +aux residual (fp32)
//      2 = delta epilogue -> pz bf16 (p1=W_dt, p2=b_dt, p3=bc2, aux=xs64)
//      5 = full bf16 write -> pz
template<int BM, int BN, int WGM, int WGN, int EPI>
__global__ __launch_bounds__(256) void gemm_bf16(
    const u16* __restrict__ A, const u16* __restrict__ Bt,
    float* __restrict__ C, int M, int N, int K, const float* __restrict__ aux,
    const float* __restrict__ p1, const float* __restrict__ p2,
    const float* __restrict__ p3, u16* __restrict__ pz) {
  constexpr int MF = BM / (16 * WGM);
  constexpr int NF = BN / (16 * WGN);
  constexpr int AR = BM / 32;   // A staging rounds
  constexpr int BR = BN / 32;   // B staging rounds
  constexpr int HALF = (BM + BN) * 128;   // bytes per buffer
  __shared__ __align__(16) char smem[2 * HALF];

  int tid = threadIdx.x;
  int lane = tid & 63;
  int wid = tid >> 6;
  int m0 = blockIdx.y * BM, n0 = blockIdx.x * BN;
  int wr = wid / WGN, wc = wid % WGN;

  f32x4 acc[MF][NF];
  #pragma unroll
  for (int i = 0; i < MF; ++i)
    #pragma unroll
    for (int j = 0; j < NF; ++j) acc[i][j] = f32x4{0.f, 0.f, 0.f, 0.f};

  int srow = tid >> 3;            // 0..31 within a staging round
  int schunk = tid & 7;           // LDS 16B-chunk index within row
  int wavebase = (tid & 192) * 16;   // wave-uniform LDS byte base (wid*1024)
  int arow = lane & 15;
  int kgrp = lane >> 4;           // 0..3
  int sw = (lane & 7) << 4;       // read-side XOR swizzle

  // stage tile (k-offset k0) into LDS buffer `base`
  auto stage = [&](int k0, char* base) {
    #pragma unroll
    for (int r = 0; r < AR; ++r) {
      int row = r * 32 + srow;
      int chunk = schunk ^ (row & 7);
      const u16* g = A + (size_t)(m0 + row) * K + k0 + chunk * 8;
      __builtin_amdgcn_global_load_lds(
          (const __attribute__((address_space(1))) void*)g,
          (__attribute__((address_space(3))) void*)(base + r * 4096 + wavebase),
          16, 0, 0);
    }
    #pragma unroll
    for (int r = 0; r < BR; ++r) {
      int row = r * 32 + srow;
      int chunk = schunk ^ (row & 7);
      const u16* g = Bt + (size_t)(n0 + row) * K + k0 + chunk * 8;
      __builtin_amdgcn_global_load_lds(
          (const __attribute__((address_space(1))) void*)g,
          (__attribute__((address_space(3))) void*)(base + BM * 128 + r * 4096 + wavebase),
          16, 0, 0);
    }
  };

  // MFMA over one staged K-tile in buffer `base`
  auto compute = [&](const char* base) {
    const char* Asm = base;
    const char* Bsm = base + BM * 128;
    #pragma unroll
    for (int ks = 0; ks < 2; ++ks) {
      bf16x8 af[MF], bg[NF];
      #pragma unroll
      for (int i = 0; i < MF; ++i) {
        int row = wr * MF * 16 + i * 16 + arow;
        int off = row * 128 + ((((ks * 4 + kgrp) * 16)) ^ sw);
        af[i] = *(const bf16x8*)(Asm + off);
      }
      #pragma unroll
      for (int j = 0; j < NF; ++j) {
        int row = wc * NF * 16 + j * 16 + arow;
        int off = row * 128 + ((((ks * 4 + kgrp) * 16)) ^ sw);
        bg[j] = *(const bf16x8*)(Bsm + off);
      }
      #pragma unroll
      for (int i = 0; i < MF; ++i)
        #pragma unroll
        for (int j = 0; j < NF; ++j)
          acc[i][j] = __builtin_amdgcn_mfma_f32_16x16x32_bf16(af[i], bg[j], acc[i][j], 0, 0, 0);
    }
  };

  int nk = K >> 6;   // even for all call sites (12/24/6/24)
  stage(0, smem);
  asm volatile("s_waitcnt vmcnt(0)" ::: "memory");
  __builtin_amdgcn_s_barrier();
  for (int t = 0; t < nk; t += 2) {
    stage((t + 1) << 6, smem + HALF);        // prefetch t+1 (t+1<nk: nk even)
    compute(smem);                            // tile t
    asm volatile("s_waitcnt vmcnt(0)" ::: "memory");
    __builtin_amdgcn_s_barrier();
    if (t + 2 < nk) stage((t + 2) << 6, smem);  // prefetch t+2
    compute(smem + HALF);                     // tile t+1
    asm volatile("s_waitcnt vmcnt(0)" ::: "memory");
    __builtin_amdgcn_s_barrier();
  }

  // epilogue: D row=(lane>>4)*4+r, col=lane&15 (m89-verified)
  int crow0 = m0 + wr * MF * 16 + (lane >> 4) * 4;
  int ccol0 = n0 + wc * NF * 16 + (lane & 15);
  #pragma unroll
  for (int i = 0; i < MF; ++i) {
    #pragma unroll
    for (int r = 0; r < 4; ++r) {
      int row = crow0 + i * 16 + r;
      float araw = 0.f;
      if (EPI == 2) araw = aux[(size_t)row * 64];
      #pragma unroll
      for (int j = 0; j < NF; ++j) {
        int col = ccol0 + j * 16;
        float v = acc[i][j][r];
        if (EPI == 0) {
          C[(size_t)row * N + col] = v;
        } else if (EPI == 1) {
          C[(size_t)row * N + col] = v + aux[(size_t)row * N + col];
        } else if (EPI == 2) {
          float raw = fmaf(araw, p1[col], p2[col]);
          float sp = fmaxf(raw, 0.f) + __logf(1.f + __expf(-fabsf(raw)));
          float mod = 1.f / (1.f + __expf(-(v + p3[col])));
          pz[(size_t)row * N + col] = f2b(sp * (1.f + mod));
        } else if (EPI == 5) {
          pz[(size_t)row * N + col] = f2b(v);
        }
      }
    }
  }
}

// ---------------- 3. depthwise causal conv (k=4) + bias + SiLU ---------------
// reads xzb [ROWS][D2] bf16 (x_proj = cols 0..1535); writes bf16 xcb
__global__ __launch_bounds__(256) void conv_silu_kernel(const u16* __restrict__ xzb,
    const float* __restrict__ cw, const float* __restrict__ cb,
    u16* __restrict__ xcb) {
  long idx = (long)blockIdx.x * 256 + threadIdx.x;
  if (idx >= (long)ROWS * DINNER) return;
  int d = (int)(idx % DINNER);
  long r = idx / DINNER;
  int s = (int)(r % SEQL);
  long b = r / SEQL;
  float acc = cb[d];
  #pragma unroll
  for (int j = 0; j < 4; ++j) {
    int ss = s - 3 + j;
    if (ss >= 0)
      acc = fmaf(b2f(xzb[(b * SEQL + ss) * (long)D2 + d]), cw[d * 4 + j], acc);
  }
  float sg = 1.f / (1.f + __expf(-acc));
  xcb[idx] = f2b(acc * sg);
}

// ---------------- 7. scan phase 1: per-chunk local states + sum(delta) ------
__global__ __launch_bounds__(256) void scan_p1(const u16* __restrict__ dlt,
    const u16* __restrict__ xc, const float* __restrict__ xs,
    const float* __restrict__ Af, const int* __restrict__ flag,
    float* __restrict__ Hloc, float* __restrict__ sdl) {
  __shared__ float Bsh[CL][16];
  int tid = threadIdx.x;
  int dblk = blockIdx.x % (DINNER / 256);
  int c = (blockIdx.x / (DINNER / 256)) % NC;
  int b = blockIdx.x / ((DINNER / 256) * NC);
  int d = dblk * 256 + tid;
  long row0 = (long)b * SEQL + c * CL;
  for (int e = tid; e < CL * 16; e += 256) {
    int t = e >> 4, n = e & 15;
    Bsh[t][n] = xs[(row0 + t) * 64 + 1 + n];
  }
  bool fast = (*flag == 0);
  float Ac[16];
  if (!fast) {
    #pragma unroll
    for (int n = 0; n < 16; ++n) Ac[n] = Af[d * 16 + n];
  }
  __syncthreads();
  float h[16] = {};
  float sd = 0.f;
  const u16* dp = dlt + row0 * DINNER + d;
  const u16* xp = xc + row0 * DINNER + d;
  if (fast) {
    for (int t = 0; t < CL; ++t) {
      float dl = b2f(dp[(long)t * DINNER]);
      float xv = b2f(xp[(long)t * DINNER]);
      sd += dl;
      float dx = dl * xv;
      float E[16]; build_E_fast(dl, E);
      #pragma unroll
      for (int n = 0; n < 16; ++n) h[n] = fmaf(E[n], h[n], dx * Bsh[t][n]);
    }
  } else {
    for (int t = 0; t < CL; ++t) {
      float dl = b2f(dp[(long)t * DINNER]);
      float xv = b2f(xp[(long)t * DINNER]);
      sd += dl;
      float dx = dl * xv;
      #pragma unroll
      for (int n = 0; n < 16; ++n)
        h[n] = fmaf(__expf(dl * Ac[n]), h[n], dx * Bsh[t][n]);
    }
  }
  long base = ((long)(b * NC + c) * DINNER + d) * 16;
  #pragma unroll
  for (int n = 0; n < 16; ++n) Hloc[base + n] = h[n];
  sdl[(long)(b * NC + c) * DINNER + d] = sd;
}

// ---------------- 8. scan phase 2: carry sweep -------------------------------
__global__ __launch_bounds__(256) void scan_carry(float* __restrict__ Hloc,
    const float* __restrict__ sdl, const float* __restrict__ Af) {
  long g = (long)blockIdx.x * 256 + threadIdx.x;
  if (g >= (long)NBATCH * DINNER * 16) return;
  int n = (int)(g & 15);
  int d = (int)((g >> 4) % DINNER);
  int b = (int)(g / (16L * DINNER));
  float An = Af[d * 16 + n];
  float s = 0.f;
  for (int c = 0; c < NC; ++c) {
    long off = ((long)(b * NC + c) * DINNER + d) * 16 + n;
    float H = Hloc[off];
    float sdv = sdl[(long)(b * NC + c) * DINNER + d];
    Hloc[off] = s;
    s = fmaf(__expf(An * sdv), s, H);
  }
}

// ---------------- 9. scan phase 3: replay + fused gate -> y2 (bf16) ----------
__global__ __launch_bounds__(256) void scan_p3(const u16* __restrict__ dlt,
    const u16* __restrict__ xc, const float* __restrict__ xs,
    const float* __restrict__ Af, const int* __restrict__ flag,
    const float* __restrict__ Hloc, const u16* __restrict__ xzb,
    const float* __restrict__ Dskip, u16* __restrict__ y2) {
  __shared__ float Bsh[CL][16];
  __shared__ float Csh[CL][16];
  int tid = threadIdx.x;
  int dblk = blockIdx.x % (DINNER / 256);
  int c = (blockIdx.x / (DINNER / 256)) % NC;
  int b = blockIdx.x / ((DINNER / 256) * NC);
  int d = dblk * 256 + tid;
  long row0 = (long)b * SEQL + c * CL;
  for (int e = tid; e < CL * 16; e += 256) {
    int t = e >> 4, n = e & 15;
    long rr = row0 + t;
    Bsh[t][n] = xs[rr * 64 + 1 + n];
    Csh[t][n] = xs[rr * 64 + 17 + n];
  }
  bool fast = (*flag == 0);
  float Ac[16];
  if (!fast) {
    #pragma unroll
    for (int n = 0; n < 16; ++n) Ac[n] = Af[d * 16 + n];
  }
  __syncthreads();
  float h[16];
  long base = ((long)(b * NC + c) * DINNER + d) * 16;
  #pragma unroll
  for (int n = 0; n < 16; ++n) h[n] = Hloc[base + n];
  float Dv = Dskip[d];
  const u16* dp = dlt + row0 * DINNER + d;
  const u16* xp = xc + row0 * DINNER + d;
  const u16* zp = xzb + row0 * D2 + DINNER + d;   // z = cols 1536.. of xzb
  u16* yp = y2 + row0 * DINNER + d;
  if (fast) {
    for (int t = 0; t < CL; ++t) {
      float dl = b2f(dp[(long)t * DINNER]);
      float xv = b2f(xp[(long)t * DINNER]);
      float dx = dl * xv;
      float E[16]; build_E_fast(dl, E);
      float y = 0.f;
      #pragma unroll
      for (int n = 0; n < 16; ++n) {
        h[n] = fmaf(E[n], h[n], dx * Bsh[t][n]);
        y = fmaf(h[n], Csh[t][n], y);
      }
      float yv = fmaf(xv, Dv, y);
      float zv = b2f(zp[(long)t * D2]);
      float sz = zv / (1.f + __expf(-zv));
      yp[(long)t * DINNER] = f2b(yv * sz);
    }
  } else {
    for (int t = 0; t < CL; ++t) {
      float dl = b2f(dp[(long)t * DINNER]);
      float xv = b2f(xp[(long)t * DINNER]);
      float dx = dl * xv;
      float y = 0.f;
      #pragma unroll
      for (int n = 0; n < 16; ++n) {
        h[n] = fmaf(__expf(dl * Ac[n]), h[n], dx * Bsh[t][n]);
        y = fmaf(h[n], Csh[t][n], y);
      }
      float yv = fmaf(xv, Dv, y);
      float zv = b2f(zp[(long)t * D2]);
      float sz = zv / (1.f + __expf(-zv));
      yp[(long)t * DINNER] = f2b(yv * sz);
    }
  }
}

// ---------------- launch ----------------
extern "C" void kernel_launch(void* const* d_in, const int* in_sizes, int n_in,
                              void* d_out, int out_size, void* d_ws, size_t ws_size,
                              hipStream_t stream) {
  const float* x      = (const float*)d_in[0];
  const float* imp    = (const float*)d_in[1];
  const float* ln_g   = (const float*)d_in[2];
  const float* ln_b   = (const float*)d_in[3];
  const float* W_in   = (const float*)d_in[4];
  const float* conv_w = (const float*)d_in[5];
  const float* conv_b = (const float*)d_in[6];
  const float* W_x    = (const float*)d_in[7];
  const float* W_dt   = (const float*)d_in[8];
  const float* b_dt   = (const float*)d_in[9];
  const float* Wc1    = (const float*)d_in[10];
  const float* bc1    = (const float*)d_in[11];
  const float* Wc2    = (const float*)d_in[12];
  const float* bc2    = (const float*)d_in[13];
  const float* A_log  = (const float*)d_in[14];
  const float* Dskip  = (const float*)d_in[15];
  const float* W_out  = (const float*)d_in[16];
  float* out = (float*)d_out;

  char* ws = (char*)d_ws;
  u16*   xzb    = (u16*)  (ws);                 // 4096*3072 bf16  (25165824)
  u16*   xcb    = (u16*)  (ws + 25165824L);     // 4096*1536 bf16  (12582912)
  u16*   dltb   = (u16*)  (ws + 37748736L);     // 4096*1536 bf16  (12582912)
  float* xs64   = (float*)(ws + 50331648L);     // 4096*64 f32     (1048576)
  u16*   hid    = (u16*)  (ws + 51380224L);     // 4096*384 bf16   (3145728)
  u16*   xnb    = (u16*)  (ws + 54525952L);     // 4096*768 bf16   (6291456)
  u16*   y2     = (u16*)  (ws + 60817408L);     // 4096*1536 bf16  (12582912)
  float* Hloc   = (float*)(ws + 73400320L);     // 2*64*1536*16 f32 (12582912)
  float* sdl    = (float*)(ws + 85983232L);     // 2*64*1536 f32   (786432)
  u16*   Wt_in  = (u16*)  (ws + 86769664L);     // 3072*768 bf16   (4718592)
  u16*   Wt_c2  = (u16*)  (ws + 91488256L);     // 1536*384 bf16   (1179648)
  u16*   Wt_out = (u16*)  (ws + 92667904L);     // 768*1536 bf16   (2359296)
  u16*   Wxt    = (u16*)  (ws + 95027200L);     // 64*1536 bf16    (196608)
  float* Af     = (float*)(ws + 95223808L);     // 1536*16 f32     (98304)
  int*   flag   = (int*)  (ws + 95322112L);     // 4

  // 0. combined prep: weight transposes + wxt + hid + LN  (input-only deps)
  prep_kernel<<<14656, 256, 0, stream>>>(
      W_in, Wt_in, Wc2, Wt_c2, W_out, Wt_out, W_x, Wxt,
      imp, Wc1, bc1, hid, x, ln_g, ln_b, xnb);
  // 0b. Af + structure flag (single block, no memset needed)
  af_kernel<<<1, 256, 0, stream>>>(A_log, Af, flag);

  // 2. xz = xn @ W_in (4096 x 768 x 3072) -> xzb bf16 (x_proj | z)
  gemm_bf16<128,128,2,2,5><<<dim3(D2/128, ROWS/128), 256, 0, stream>>>(
      xnb, Wt_in, nullptr, ROWS, D2, DMODEL, nullptr, nullptr, nullptr, nullptr, xzb);
  // 3. conv + SiLU -> xcb (bf16)
  conv_silu_kernel<<<(ROWS * DINNER) / 256, 256, 0, stream>>>(xzb, conv_w, conv_b, xcb);
  // 4. x_ssm = xc @ W_x  (MFMA, N padded 33->64) -> xs64   (BM=32: 128 blocks)
  gemm_bf16<32,64,1,4,0><<<dim3(1, ROWS/32), 256, 0, stream>>>(
      xcb, Wxt, xs64, ROWS, 64, DINNER, nullptr, nullptr, nullptr, nullptr, nullptr);
  // 6. dlt = softplus(xs64[:,0]*Wdt+bdt) * (1+sigmoid(hid@Wc2 + bc2)) -> bf16
  gemm_bf16<64,128,1,4,2><<<dim3(DINNER/128, ROWS/64), 256, 0, stream>>>(
      hid, Wt_c2, nullptr, ROWS, DINNER, DHID, xs64, W_dt, b_dt, bc2, dltb);
  // 7-9. chunked scan
  scan_p1<<<NBATCH * NC * (DINNER / 256), 256, 0, stream>>>(dltb, xcb, xs64, Af, flag, Hloc, sdl);
  scan_carry<<<(NBATCH * DINNER * 16) / 256, 256, 0, stream>>>(Hloc, sdl, Af);
  scan_p3<<<NBATCH * NC * (DINNER / 256), 256, 0, stream>>>(dltb, xcb, xs64, Af, flag, Hloc, xzb, Dskip, y2);
  // 10. out = y2 @ W_out + residual  (4096 x 1536 x 768)
  gemm_bf16<64,64,1,4,1><<<dim3(DMODEL/64, ROWS/64), 256, 0, stream>>>(
      y2, Wt_out, out, ROWS, DMODEL, DINNER, x, nullptr, nullptr, nullptr, nullptr);
}